// Round 12
// baseline (595.500 us; speedup 1.0000x reference)
//
#include <hip/hip_runtime.h>
#include <math.h>

// Problem constants
#define TT    48
#define BB    96
#define DG    192
#define DH    384
#define NSTEP 47     // T-1 scan steps
#define SETI  3      // inner settling iterations
#define NT    512    // threads per block (8 waves = 2/SIMD -> 256-reg budget)
#define NWAVE 8      // 512/64
#define NG    32     // 16-lane groups per block
#define RPG   12     // rows per group (384/32)
#define LWROWS 192   // Wh rows staged in LDS (rows 0..191)
#define LWSTR  97    // uint2 stride per staged row (96 + 1 pad)
#define PNT   256    // prep block size
#define PTT   24     // t's per prep block (grid y = 2)

typedef unsigned short ushort_t;
typedef float f32x2 __attribute__((ext_vector_type(2)));

// ---------- DPP-based reductions ----------
template <int CTRL, int RM>
__device__ __forceinline__ float dppadd(float acc, float x) {
  int t = __builtin_amdgcn_update_dpp(0, __float_as_int(x), CTRL, RM, 0xF, false);
  return acc + __int_as_float(t);
}
__device__ __forceinline__ float row16_sum(float v) {
  v = dppadd<0x128, 0xF>(v, v);  // row_ror:8
  v = dppadd<0x124, 0xF>(v, v);  // row_ror:4
  v = dppadd<0x122, 0xF>(v, v);  // row_ror:2
  v = dppadd<0x121, 0xF>(v, v);  // row_ror:1
  return v;
}
__device__ __forceinline__ float wave_sum63(float v) {
  v = row16_sum(v);
  v = dppadd<0x142, 0xA>(v, v);  // row_bcast:15
  v = dppadd<0x143, 0xC>(v, v);  // row_bcast:31
  return v;
}
__device__ __forceinline__ float blo(unsigned u) { return __uint_as_float(u << 16); }
__device__ __forceinline__ float bhi(unsigned u) { return __uint_as_float(u & 0xFFFF0000u); }
__device__ __forceinline__ f32x2 pkfma(f32x2 a, f32x2 b, f32x2 c) {
  return __builtin_elementwise_fma(a, b, c);
}
__device__ __forceinline__ float rowdot(const uint2* w, const f32x2 (&h2)[12]) {
  f32x2 a0 = {0.f, 0.f}, a1 = {0.f, 0.f};
#pragma unroll
  for (int c = 0; c < 6; ++c) {
    uint2 u = w[c];
    a0 = pkfma(f32x2{blo(u.x), bhi(u.x)}, h2[2 * c], a0);
    a1 = pkfma(f32x2{blo(u.y), bhi(u.y)}, h2[2 * c + 1], a1);
  }
  return row16_sum((a0.x + a1.x) + (a0.y + a1.y));
}

// gate from a completed redB row (+running Shb/Shb2): identical math to the
// old phase C, computed redundantly by every thread that needs it.
__device__ __forceinline__ void gate_from(
    const float* __restrict__ rb, float Shb, float Shb2, float kcur, float invD,
    float& aG, float& betaG, float& muG, float& rstdG, float& S2o)
{
  const float4* rb4 = (const float4*)rb;
  float S[5] = {0.f, 0.f, 0.f, 0.f, 0.f};
#pragma unroll
  for (int q = 0; q < 8; ++q) {
    float4 ch = rb4[q];
    S[(4 * q + 0) % 5] += ch.x;
    S[(4 * q + 1) % 5] += ch.y;
    S[(4 * q + 2) % 5] += ch.z;
    S[(4 * q + 3) % 5] += ch.w;
  }
  float n1 = fmaxf(sqrtf(S[1]), 1e-6f);
  float n2 = fmaxf(sqrtf(S[2]), 1e-6f);
  float R  = fminf(fmaxf(__fdividef(S[0], n1 * n2), 0.f), 1.f);
  aG   = 1.f - __expf(kcur * __logf(1.f - R));
  betaG = 1.f - aG * aG;
  muG  = (betaG * Shb + aG * S[4]) * invD;
  float Exx = (betaG * betaG * Shb2 + 2.f * betaG * aG * S[3] + aG * aG * S[2]) * invD;
  rstdG = rsqrtf(Exx - muG * muG + 1e-5f);
  S2o = S[2];
}

// FULL matvec: group g owns rows r = g + 32p. Rows p=0..5 from LDS-staged Wh;
// p=6..11 stream from L2 as a 3-deep 2-row-batch pipeline (R10, no spill).
__device__ __forceinline__ void matvec_full(
    const uint2* __restrict__ lwh, const ushort_t* __restrict__ Wh_b,
    const float* __restrict__ hs, const float* __restrict__ gzs,
    float* __restrict__ hbs, float& s1, float& s2,
    int g, int lane16, bool with_h)
{
  float rs[RPG];
  if (with_h) {
    const uint2* wsrc = (const uint2*)Wh_b;
    uint2 uw0[12];
#pragma unroll
    for (int pp = 0; pp < 2; ++pp)
#pragma unroll
      for (int c = 0; c < 6; ++c)
        uw0[pp * 6 + c] =
            wsrc[(size_t)(g + NG * (6 + pp)) * (DH / 4) + lane16 + 16 * c];
    f32x2 h2[12];
    const float4* h4 = (const float4*)hs;
#pragma unroll
    for (int c = 0; c < 6; ++c) {
      float4 hh = h4[lane16 + 16 * c];
      h2[2 * c]     = f32x2{hh.x, hh.y};
      h2[2 * c + 1] = f32x2{hh.z, hh.w};
    }
    uint2 uw1[12];
#pragma unroll
    for (int pp = 0; pp < 2; ++pp)
#pragma unroll
      for (int c = 0; c < 6; ++c)
        uw1[pp * 6 + c] =
            wsrc[(size_t)(g + NG * (8 + pp)) * (DH / 4) + lane16 + 16 * c];
#pragma unroll
    for (int p = 0; p < 6; ++p) {
      const int r = g + NG * p;
      f32x2 a0 = {0.f, 0.f}, a1 = {0.f, 0.f};
#pragma unroll
      for (int c = 0; c < 6; ++c) {
        uint2 u = lwh[r * LWSTR + lane16 + 16 * c];
        a0 = pkfma(f32x2{blo(u.x), bhi(u.x)}, h2[2 * c], a0);
        a1 = pkfma(f32x2{blo(u.y), bhi(u.y)}, h2[2 * c + 1], a1);
      }
      rs[p] = row16_sum((a0.x + a1.x) + (a0.y + a1.y));
    }
    rs[6] = rowdot(uw0, h2);
    rs[7] = rowdot(uw0 + 6, h2);
    uint2 uw2[12];
#pragma unroll
    for (int pp = 0; pp < 2; ++pp)
#pragma unroll
      for (int c = 0; c < 6; ++c)
        uw2[pp * 6 + c] =
            wsrc[(size_t)(g + NG * (10 + pp)) * (DH / 4) + lane16 + 16 * c];
    rs[8] = rowdot(uw1, h2);
    rs[9] = rowdot(uw1 + 6, h2);
    rs[10] = rowdot(uw2, h2);
    rs[11] = rowdot(uw2 + 6, h2);
  } else {
#pragma unroll
    for (int p = 0; p < RPG; ++p) rs[p] = 0.f;
  }
  if (lane16 == 0) {
#pragma unroll
    for (int p = 0; p < RPG; ++p) {
      const int r = g + NG * p;
      float vv = rs[p] + gzs[r];
      hbs[r] = vv;
      s1 += vv;
      s2 += vv * vv;
    }
  }
}

// Fallback matvec (no workspace): fp32 weights streamed, z from LDS.
__device__ __forceinline__ void matvec_ref(
    const float* __restrict__ Wh_f, const float* __restrict__ Wg_f,
    const float* __restrict__ hs, const float* __restrict__ zsh,
    const float (&bias)[RPG], float* __restrict__ hbs,
    float& s1, float& s2, int g, int lane16, bool with_h)
{
  f32x2 h2[12];
  if (with_h) {
    const float4* h4 = (const float4*)hs;
#pragma unroll
    for (int c = 0; c < 6; ++c) {
      float4 hh = h4[lane16 + 16 * c];
      h2[2 * c]     = f32x2{hh.x, hh.y};
      h2[2 * c + 1] = f32x2{hh.z, hh.w};
    }
  }
  float4 zz[3];
  const float4* z4 = (const float4*)zsh;
#pragma unroll
  for (int c = 0; c < 3; ++c) zz[c] = z4[lane16 + 16 * c];
#pragma unroll 2
  for (int p = 0; p < RPG; ++p) {
    const int r = g + NG * p;
    f32x2 a0 = {0.f, 0.f}, a1 = {0.f, 0.f};
    const float4* wg = (const float4*)Wg_f + (size_t)r * (DG / 4);
#pragma unroll
    for (int c = 0; c < 3; ++c) {
      float4 w = wg[lane16 + 16 * c];
      a0 = pkfma(f32x2{w.x, w.y}, f32x2{zz[c].x, zz[c].y}, a0);
      a1 = pkfma(f32x2{w.z, w.w}, f32x2{zz[c].z, zz[c].w}, a1);
    }
    if (with_h) {
      const float4* wh = (const float4*)Wh_f + (size_t)r * (DH / 4);
#pragma unroll
      for (int c = 0; c < 6; ++c) {
        float4 w = wh[lane16 + 16 * c];
        a0 = pkfma(f32x2{w.x, w.y}, h2[2 * c], a0);
        a1 = pkfma(f32x2{w.z, w.w}, h2[2 * c + 1], a1);
      }
    }
    float acc = row16_sum((a0.x + a1.x) + (a0.y + a1.y));
    if (lane16 == 0) {
      float vv = acc + bias[p];
      hbs[r] = vv;
      s1 += vv;
      s2 += vv * vv;
    }
  }
}

template <bool FULL>
__global__ __launch_bounds__(NT, 2) void fw_rnn_kernel(
    const float* __restrict__ z_seq,    // [T, B, DG]
    const float* __restrict__ Wh_f,     // [DH, DH] fp32
    const float* __restrict__ Wg_f,     // [DH, DG] fp32
    const ushort_t* __restrict__ Wh_b,  // bf16 copy (ws), FULL only
    const float* __restrict__ gz,       // [T, B, DH] Wg.z + b_h, FULL only
    const float* __restrict__ b_h,
    const float* __restrict__ ln_g,
    const float* __restrict__ ln_b,
    const float* __restrict__ alpha_fw,
    float* __restrict__ out)            // [B, DH]
{
  __shared__ __align__(16) uint2 lwh[LWROWS * LWSTR];  // 149 KB staged Wh
  __shared__ __align__(16) float hs[DH];
  __shared__ __align__(16) float hbs[DH];
  __shared__ __align__(16) float ahs[DH];              // settle ah broadcast
  __shared__ __align__(16) float lngs[DH];             // ln_g staged
  __shared__ __align__(16) float lnbs[DH];             // ln_b staged
  __shared__ __align__(16) float gzs[DH];              // FULL: Wg.z+b_h for t
  __shared__ __align__(16) float zsh[DG];              // !FULL only
  __shared__ float wlam[NSTEP];
  __shared__ __align__(16) float carr[48];             // entries >= t stay 0
  __shared__ __align__(16) float redA[NWAVE * 2];
  __shared__ __align__(16) float redB[2][32];          // rows padded to 32

  const int tid    = threadIdx.x;
  const int b      = blockIdx.x;
  const int lane   = tid & 63, wv = tid >> 6;
  const int g      = tid >> 4, lane16 = tid & 15;
  const bool owner = (tid < DH);
  const bool zst   = (!FULL) && (tid >= DH) && (tid < DH + DG / 4);

  // stage Wh rows 0..191 into LDS (once)
  if (FULL) {
    const uint2* src = (const uint2*)Wh_b;
    for (int i = tid; i < LWROWS * 96; i += NT) {
      int row = i / 96, col = i - 96 * (i / 96);
      lwh[row * LWSTR + col] = src[(size_t)row * 96 + col];
    }
  }

  float bias[RPG];
#pragma unroll
  for (int p = 0; p < RPG; ++p) bias[p] = 0.f;
  if (!FULL && lane16 == 0) {
#pragma unroll
    for (int p = 0; p < RPG; ++p) bias[p] = b_h[g + NG * p];
  }
  float g_i = 0.f, be_i = 0.f;
  if (owner) {
    g_i = ln_g[tid]; be_i = ln_b[tid];
    lngs[tid] = g_i; lnbs[tid] = be_i;
  }

  const float af   = alpha_fw[0];
  const float kcur = (af >= 0.f) ? (1.f + log1pf(expf(af)))
                                 : (1.f / (1.f + log1pf(expf(-af))));
  const float invD = 1.0f / (float)DH;

  // persistent owner state (AGPR-resident)
  float hcol[48];
#pragma unroll
  for (int q = 0; q < 48; ++q) hcol[q] = 0.f;
  float4 hregA[6], hregB[6];
#pragma unroll
  for (int c = 0; c < 6; ++c) {
    hregA[c] = float4{0.f, 0.f, 0.f, 0.f};
    hregB[c] = float4{0.f, 0.f, 0.f, 0.f};
  }

  if (FULL && tid < DH / 4)
    ((float4*)gzs)[tid] = ((const float4*)(gz + (size_t)b * DH))[tid];
  if (!FULL && tid < DG / 4)
    ((float4*)zsh)[tid] = ((const float4*)(z_seq + (size_t)b * DG))[tid];
  if (tid < 48) carr[tid] = 0.f;
  if (tid < 2) { redB[tid][30] = 0.f; redB[tid][31] = 0.f; }
  __syncthreads();

  float Shb = 0.f, Shb2 = 0.f;

  for (int t = 0; t < NSTEP; ++t) {
    // ---------- phase M: prefetch + matvec + LN-stat partials ----------
    float4 gzn = {0.f, 0.f, 0.f, 0.f};
    if (FULL && tid < DH / 4)
      gzn = ((const float4*)(gz + ((size_t)(t + 1) * BB + b) * DH))[tid];
    float4 znext;
    if (zst)
      znext = ((const float4*)(z_seq + ((size_t)(t + 1) * BB + b) * DG))[tid - DH];

    float s1 = 0.f, s2 = 0.f;
    if (FULL)
      matvec_full(lwh, Wh_b, hs, gzs, hbs, s1, s2, g, lane16, t > 0);
    else
      matvec_ref(Wh_f, Wg_f, hs, zsh, bias, hbs, s1, s2, g, lane16, t > 0);

    // snapshot committed rows (hs == h_{t-1} until epilogue)
    if (t > 0) {
      if (g == t - 1) {
#pragma unroll
        for (int c = 0; c < 6; ++c) hregA[c] = ((const float4*)hs)[lane16 + 16 * c];
      }
      if (g + NG == t - 1) {
#pragma unroll
        for (int c = 0; c < 6; ++c) hregB[c] = ((const float4*)hs)[lane16 + 16 * c];
      }
    }
    {
      float v0 = wave_sum63(s1);
      float v1 = wave_sum63(s2);
      if (lane == 63) { redA[wv * 2] = v0; redA[wv * 2 + 1] = v1; }
    }
    __syncthreads();  // (a)

    // all threads: h_base stats
    {
      float S1 = 0.f, S2 = 0.f;
      const float4* ra4 = (const float4*)redA;
#pragma unroll
      for (int q = 0; q < 4; ++q) {
        float4 ch = ra4[q];
        S1 += ch.x + ch.z;
        S2 += ch.y + ch.w;
      }
      Shb = S1; Shb2 = S2;
    }
    const float m0    = Shb * invD;
    const float rstd0 = rsqrtf(Shb2 * invD - m0 * m0 + 1e-5f);

    float hb = 0.f, hsv = 0.f, ah = 0.f;
    if (owner) {
      hb  = hbs[tid];
      hsv = fmaxf((hb - m0) * rstd0 * g_i + be_i, 0.f);
    }
    if (t == 0) {
      // A == 0: settling is identity. Commit + housekeeping.
      if (owner) { hs[tid] = hsv; hcol[0] = hsv; }
      if (tid == 0) wlam[0] = 0.5f;
      if (FULL && tid < DH / 4) ((float4*)gzs)[tid] = gzn;
      if (zst) ((float4*)zsh)[tid - DH] = znext;
      __syncthreads();
      continue;
    }

    // ---------- settling: 2 barriers per settle ----------
    float aG = 0.f, betaG = 1.f, muG = m0, rstdG = rstd0, S2g = 0.f;
#pragma unroll
    for (int s = 0; s < SETI; ++s) {
      // phase A_s (runs in the same region as the gate of settle s-1):
      if (s > 0) {
        gate_from(redB[(s - 1) & 1], Shb, Shb2, kcur, invD,
                  aG, betaG, muG, rstdG, S2g);
        if (owner)
          hsv = fmaxf((betaG * hb + aG * ah - muG) * rstdG * g_i + be_i, 0.f);
      }
      if (g < t) {
        // reconstruct h_s inline from hbs (+ahs for s>0) and LN params
        float4 ssv[6];
        const float4* hb4 = (const float4*)hbs;
        const float4* ah4 = (const float4*)ahs;
        const float4* lg4 = (const float4*)lngs;
        const float4* lb4 = (const float4*)lnbs;
#pragma unroll
        for (int c = 0; c < 6; ++c) {
          float4 hbv = hb4[lane16 + 16 * c];
          float4 lg  = lg4[lane16 + 16 * c];
          float4 lb  = lb4[lane16 + 16 * c];
          float4 x;
          if (s == 0) {
            x = hbv;
          } else {
            float4 av = ah4[lane16 + 16 * c];
            x.x = betaG * hbv.x + aG * av.x;
            x.y = betaG * hbv.y + aG * av.y;
            x.z = betaG * hbv.z + aG * av.z;
            x.w = betaG * hbv.w + aG * av.w;
          }
          const float mu = (s == 0) ? m0 : muG;
          const float rs = (s == 0) ? rstd0 : rstdG;
          ssv[c].x = fmaxf((x.x - mu) * rs * lg.x + lb.x, 0.f);
          ssv[c].y = fmaxf((x.y - mu) * rs * lg.y + lb.y, 0.f);
          ssv[c].z = fmaxf((x.z - mu) * rs * lg.z + lb.z, 0.f);
          ssv[c].w = fmaxf((x.w - mu) * rs * lg.w + lb.w, 0.f);
        }
        {
          f32x2 p0 = {0.f, 0.f}, p1 = {0.f, 0.f};
#pragma unroll
          for (int c = 0; c < 6; ++c) {
            p0 = pkfma(f32x2{hregA[c].x, hregA[c].y}, f32x2{ssv[c].x, ssv[c].y}, p0);
            p1 = pkfma(f32x2{hregA[c].z, hregA[c].w}, f32x2{ssv[c].z, ssv[c].w}, p1);
          }
          float p = row16_sum((p0.x + p1.x) + (p0.y + p1.y));
          if (lane16 == 0) carr[g] = p * wlam[g];
        }
        if (g + NG < t) {
          f32x2 p0 = {0.f, 0.f}, p1 = {0.f, 0.f};
#pragma unroll
          for (int c = 0; c < 6; ++c) {
            p0 = pkfma(f32x2{hregB[c].x, hregB[c].y}, f32x2{ssv[c].x, ssv[c].y}, p0);
            p1 = pkfma(f32x2{hregB[c].z, hregB[c].w}, f32x2{ssv[c].z, ssv[c].w}, p1);
          }
          float p = row16_sum((p0.x + p1.x) + (p0.y + p1.y));
          if (lane16 == 0) carr[g + NG] = p * wlam[g + NG];
        }
      }
      __syncthreads();  // (I_s): carr visible

      // phase B_s: owners compute Ah, broadcast it, 5 DPP sums
      if (owner) {
        const float4* c4 = (const float4*)carr;
        float a0 = 0.f, a1 = 0.f, a2 = 0.f, a3 = 0.f;
#pragma unroll
        for (int q = 0; q < 12; ++q) {
          float4 cc = c4[q];
          a0 = fmaf(cc.x, hcol[4 * q + 0], a0);
          a1 = fmaf(cc.y, hcol[4 * q + 1], a1);
          a2 = fmaf(cc.z, hcol[4 * q + 2], a2);
          a3 = fmaf(cc.w, hcol[4 * q + 3], a3);
        }
        ah = (a0 + a2) + (a1 + a3);
        ahs[tid] = ah;
        float v0 = wave_sum63(hsv * ah);
        float v1 = wave_sum63(hsv * hsv);
        float v2 = wave_sum63(ah * ah);
        float v3 = wave_sum63(hb * ah);
        float v4 = wave_sum63(ah);
        if (lane == 63) {
          float* rb = redB[s & 1];
          rb[wv * 5 + 0] = v0; rb[wv * 5 + 1] = v1; rb[wv * 5 + 2] = v2;
          rb[wv * 5 + 3] = v3; rb[wv * 5 + 4] = v4;
        }
      }
      __syncthreads();  // (II_s): redB + ahs visible
    }

    // ---------- epilogue: settle-2 gate + commit + housekeeping ----------
    if (owner) {
      gate_from(redB[(SETI - 1) & 1], Shb, Shb2, kcur, invD,
                aG, betaG, muG, rstdG, S2g);
      float hf = fmaxf((betaG * hb + aG * ah - muG) * rstdG * g_i + be_i, 0.f);
      hs[tid] = hf;
#pragma unroll
      for (int q = 0; q < 48; ++q)
        if (q == t) hcol[q] = hf;
    }
    if (tid < t) wlam[tid] *= 0.9f;
    else if (tid == t) wlam[tid] = 0.5f;
    if (FULL && tid < DH / 4) ((float4*)gzs)[tid] = gzn;
    if (zst) ((float4*)zsh)[tid - DH] = znext;
    __syncthreads();  // (E)
  }

  // ================= final (query) step — old proven structure ===========
  {
    float s1 = 0.f, s2 = 0.f;
    if (FULL)
      matvec_full(lwh, Wh_b, hs, gzs, hbs, s1, s2, g, lane16, true);
    else
      matvec_ref(Wh_f, Wg_f, hs, zsh, bias, hbs, s1, s2, g, lane16, true);
    if (g + NG == NSTEP - 1) {  // tau = 46 -> hregB (g = 14)
#pragma unroll
      for (int c = 0; c < 6; ++c) hregB[c] = ((const float4*)hs)[lane16 + 16 * c];
    }
    {
      float v0 = wave_sum63(s1);
      float v1 = wave_sum63(s2);
      if (lane == 63) { redA[wv * 2] = v0; redA[wv * 2 + 1] = v1; }
    }
    __syncthreads();

    float hb = 0.f, hv = 0.f;
    if (owner) {
      float S1 = 0.f, S2 = 0.f;
      const float4* ra4 = (const float4*)redA;
#pragma unroll
      for (int q = 0; q < 4; ++q) {
        float4 ch = ra4[q];
        S1 += ch.x + ch.z;
        S2 += ch.y + ch.w;
      }
      Shb = S1; Shb2 = S2;
      hb = hbs[tid];
      float m   = S1 * invD;
      float var = S2 * invD - m * m;
      hv = fmaxf((hb - m) * rsqrtf(var + 1e-5f) * g_i + be_i, 0.f);
      hs[tid] = hv;
    }
    __syncthreads();

    for (int s = 0; s < SETI; ++s) {
      {
        float4 ss[6];
        const float4* s4 = (const float4*)hs;
#pragma unroll
        for (int c = 0; c < 6; ++c) ss[c] = s4[lane16 + 16 * c];
        {
          f32x2 p0 = {0.f, 0.f}, p1 = {0.f, 0.f};
#pragma unroll
          for (int c = 0; c < 6; ++c) {
            p0 = pkfma(f32x2{hregA[c].x, hregA[c].y}, f32x2{ss[c].x, ss[c].y}, p0);
            p1 = pkfma(f32x2{hregA[c].z, hregA[c].w}, f32x2{ss[c].z, ss[c].w}, p1);
          }
          float p = row16_sum((p0.x + p1.x) + (p0.y + p1.y));
          if (lane16 == 0) carr[g] = p * wlam[g];
        }
        if (g + NG < NSTEP) {
          f32x2 p0 = {0.f, 0.f}, p1 = {0.f, 0.f};
#pragma unroll
          for (int c = 0; c < 6; ++c) {
            p0 = pkfma(f32x2{hregB[c].x, hregB[c].y}, f32x2{ss[c].x, ss[c].y}, p0);
            p1 = pkfma(f32x2{hregB[c].z, hregB[c].w}, f32x2{ss[c].z, ss[c].w}, p1);
          }
          float p = row16_sum((p0.x + p1.x) + (p0.y + p1.y));
          if (lane16 == 0) carr[g + NG] = p * wlam[g + NG];
        }
      }
      __syncthreads();

      float ah = 0.f;
      if (owner) {
        const float4* c4 = (const float4*)carr;
        float a0 = 0.f, a1 = 0.f, a2 = 0.f, a3 = 0.f;
#pragma unroll
        for (int q = 0; q < 12; ++q) {
          float4 cc = c4[q];
          a0 = fmaf(cc.x, hcol[4 * q + 0], a0);
          a1 = fmaf(cc.y, hcol[4 * q + 1], a1);
          a2 = fmaf(cc.z, hcol[4 * q + 2], a2);
          a3 = fmaf(cc.w, hcol[4 * q + 3], a3);
        }
        ah = (a0 + a2) + (a1 + a3);
        float v0 = wave_sum63(ah);
        float v1 = wave_sum63(ah * ah);
        float v2 = wave_sum63(hb * ah);
        if (lane == 63) {
          float* rb = redB[s & 1];
          rb[wv * 5 + 0] = v0; rb[wv * 5 + 1] = v1; rb[wv * 5 + 2] = v2;
        }
      }
      __syncthreads();

      if (owner) {
        const float4* rb4 = (const float4*)redB[s & 1];
        float S[5] = {0.f, 0.f, 0.f, 0.f, 0.f};
#pragma unroll
        for (int q = 0; q < 8; ++q) {
          float4 ch = rb4[q];
          S[(4 * q + 0) % 5] += ch.x;
          S[(4 * q + 1) % 5] += ch.y;
          S[(4 * q + 2) % 5] += ch.z;
          S[(4 * q + 3) % 5] += ch.w;
        }
        float Sx  = Shb + S[0];
        float Sxx = Shb2 + 2.f * S[2] + S[1];
        float mu  = Sx * invD;
        float var = Sxx * invD - mu * mu;
        float xv  = hb + ah;
        hv = fmaxf((xv - mu) * rsqrtf(var + 1e-5f) * g_i + be_i, 0.f);
        if (s < SETI - 1) hs[tid] = hv;
      }
      if (s < SETI - 1) __syncthreads();
    }

    if (owner) out[(size_t)b * DH + tid] = hv;
  }
}

// Prologue (one launch): bf16-convert W_h AND compute gz (R11 version).
__global__ __launch_bounds__(PNT) void prep_kernel(
    const float* __restrict__ z_seq, const float* __restrict__ Wg,
    const float* __restrict__ W_h, const float* __restrict__ b_h,
    ushort_t* __restrict__ Whb, float* __restrict__ gz)
{
  __shared__ __align__(16) float zsh[PTT * DG];
  const int tid = threadIdx.x, b = blockIdx.x;
  const int t0 = blockIdx.y * PTT;
  const int g = tid >> 4, lane16 = tid & 15;

  {
    int lid = ((blockIdx.y * BB + blockIdx.x) * PNT + tid) * 3;
#pragma unroll
    for (int k = 0; k < 3; ++k) {
      int idx = lid + k;
      if (idx < DH * DH) {
        unsigned u = __float_as_uint(W_h[idx]);
        unsigned r = (u + 0x7FFFu + ((u >> 16) & 1u)) >> 16;
        Whb[idx] = (ushort_t)r;
      }
    }
  }

  for (int i = tid; i < PTT * DG / 4; i += PNT) {
    int tt = i / (DG / 4), c = i - tt * (DG / 4);
    ((float4*)zsh)[i] =
        ((const float4*)(z_seq + ((size_t)(t0 + tt) * BB + b) * DG))[c];
  }
  __syncthreads();

  for (int pp = 0; pp < 3; ++pp) {
    const int rbase = 24 * g + 8 * pp;
    float4 w[24];
#pragma unroll
    for (int j = 0; j < 8; ++j)
#pragma unroll
      for (int c = 0; c < 3; ++c)
        w[j * 3 + c] =
            ((const float4*)Wg)[(size_t)(rbase + j) * (DG / 4) + lane16 + 16 * c];
    float4 bh0 = {0.f, 0.f, 0.f, 0.f}, bh1 = {0.f, 0.f, 0.f, 0.f};
    if (lane16 == 0) {
      bh0 = ((const float4*)b_h)[rbase / 4];
      bh1 = ((const float4*)b_h)[rbase / 4 + 1];
    }
    for (int tt = 0; tt < PTT; ++tt) {
      float4 zz[3];
#pragma unroll
      for (int c = 0; c < 3; ++c)
        zz[c] = ((const float4*)zsh)[tt * (DG / 4) + lane16 + 16 * c];
      float rs[8];
#pragma unroll
      for (int j = 0; j < 8; ++j) {
        f32x2 a0 = {0.f, 0.f}, a1 = {0.f, 0.f};
#pragma unroll
        for (int c = 0; c < 3; ++c) {
          a0 = pkfma(f32x2{w[j * 3 + c].x, w[j * 3 + c].y},
                     f32x2{zz[c].x, zz[c].y}, a0);
          a1 = pkfma(f32x2{w[j * 3 + c].z, w[j * 3 + c].w},
                     f32x2{zz[c].z, zz[c].w}, a1);
        }
        rs[j] = row16_sum((a0.x + a1.x) + (a0.y + a1.y));
      }
      if (lane16 == 0) {
        float* grow = gz + ((size_t)(t0 + tt) * BB + b) * DH + rbase;
        ((float4*)grow)[0] =
            float4{rs[0] + bh0.x, rs[1] + bh0.y, rs[2] + bh0.z, rs[3] + bh0.w};
        ((float4*)grow)[1] =
            float4{rs[4] + bh1.x, rs[5] + bh1.y, rs[6] + bh1.z, rs[7] + bh1.w};
      }
    }
  }
}

extern "C" void kernel_launch(void* const* d_in, const int* in_sizes, int n_in,
                              void* d_out, int out_size, void* d_ws, size_t ws_size,
                              hipStream_t stream) {
  const float* z_seq    = (const float*)d_in[0];
  const float* W_h      = (const float*)d_in[1];
  const float* W_g      = (const float*)d_in[2];
  const float* b_h      = (const float*)d_in[3];
  const float* ln_g     = (const float*)d_in[4];
  const float* ln_b     = (const float*)d_in[5];
  const float* alpha_fw = (const float*)d_in[6];
  float* out = (float*)d_out;

  const size_t nWh = (size_t)DH * DH;                              // 147456
  const size_t bf16Bytes = nWh * sizeof(ushort_t);                 // 294912
  const size_t gzBytes   = (size_t)TT * BB * DH * sizeof(float);   // 7077888

  if (ws_size >= bf16Bytes + gzBytes) {
    ushort_t* Whb = (ushort_t*)d_ws;
    float* gz = (float*)((char*)d_ws + bf16Bytes);
    prep_kernel<<<dim3(BB, 2), dim3(PNT), 0, stream>>>(
        z_seq, W_g, W_h, b_h, Whb, gz);
    fw_rnn_kernel<true><<<dim3(BB), dim3(NT), 0, stream>>>(
        z_seq, W_h, W_g, Whb, gz, b_h, ln_g, ln_b, alpha_fw, out);
  } else {
    fw_rnn_kernel<false><<<dim3(BB), dim3(NT), 0, stream>>>(
        z_seq, W_h, W_g, nullptr, nullptr, b_h, ln_g, ln_b, alpha_fw, out);
  }
}

// Round 13
// 529.110 us; speedup vs baseline: 1.1255x; 1.1255x over previous
//
#include <hip/hip_runtime.h>
#include <math.h>

// Problem constants
#define TT    48
#define BB    96
#define DG    192
#define DH    384
#define NSTEP 47     // T-1 scan steps
#define SETI  3      // inner settling iterations
#define NT    512    // threads per block (8 waves = 2/SIMD -> 256-reg budget)
#define NWAVE 8      // 512/64
#define NG    32     // 16-lane groups per block
#define RPG   12     // rows per group (384/32)
#define LWROWS 192   // Wh rows staged in LDS (rows 0..191)
#define LWSTR  97    // uint2 stride per staged row (96 + 1 pad)
#define PNT   256    // prep block size
#define PTT   24     // t's per prep block (grid y = 2)

typedef unsigned short ushort_t;
typedef float f32x2 __attribute__((ext_vector_type(2)));

// ---------- DPP-based reductions (VALU latency, not LDS latency) ----------
template <int CTRL, int RM>
__device__ __forceinline__ float dppadd(float acc, float x) {
  int t = __builtin_amdgcn_update_dpp(0, __float_as_int(x), CTRL, RM, 0xF, false);
  return acc + __int_as_float(t);
}
__device__ __forceinline__ float row16_sum(float v) {
  v = dppadd<0x128, 0xF>(v, v);  // row_ror:8
  v = dppadd<0x124, 0xF>(v, v);  // row_ror:4
  v = dppadd<0x122, 0xF>(v, v);  // row_ror:2
  v = dppadd<0x121, 0xF>(v, v);  // row_ror:1
  return v;
}
__device__ __forceinline__ float wave_sum63(float v) {
  v = row16_sum(v);
  v = dppadd<0x142, 0xA>(v, v);  // row_bcast:15 -> rows 1,3
  v = dppadd<0x143, 0xC>(v, v);  // row_bcast:31 -> rows 2,3
  return v;
}
__device__ __forceinline__ float blo(unsigned u) { return __uint_as_float(u << 16); }
__device__ __forceinline__ float bhi(unsigned u) { return __uint_as_float(u & 0xFFFF0000u); }
__device__ __forceinline__ f32x2 pkfma(f32x2 a, f32x2 b, f32x2 c) {
  return __builtin_elementwise_fma(a, b, c);
}
__device__ __forceinline__ float rowdot(const uint2* w, const f32x2 (&h2)[12]) {
  f32x2 a0 = {0.f, 0.f}, a1 = {0.f, 0.f};
#pragma unroll
  for (int c = 0; c < 6; ++c) {
    uint2 u = w[c];
    a0 = pkfma(f32x2{blo(u.x), bhi(u.x)}, h2[2 * c], a0);
    a1 = pkfma(f32x2{blo(u.y), bhi(u.y)}, h2[2 * c + 1], a1);
  }
  return row16_sum((a0.x + a1.x) + (a0.y + a1.y));
}

// FULL matvec: group g owns rows r = g + 32p. Rows p=0..5 from LDS-staged Wh;
// p=6..11 stream from L2 as a 3-deep 2-row-batch pipeline (no scratch spill:
// max 2 batches x 24 regs + h2 = 72 transient regs). b0/b1 latency hides
// under the 6 LDS rows; b2 under b0/b1 consumption. gzs has Wg.z + b_h.
__device__ __forceinline__ void matvec_full(
    const uint2* __restrict__ lwh, const ushort_t* __restrict__ Wh_b,
    const float* __restrict__ hs, const float* __restrict__ gzs,
    float* __restrict__ hbs, float& s1, float& s2,
    int g, int lane16, bool with_h)
{
  float rs[RPG];
  if (with_h) {
    const uint2* wsrc = (const uint2*)Wh_b;
    uint2 uw0[12];
#pragma unroll
    for (int pp = 0; pp < 2; ++pp)
#pragma unroll
      for (int c = 0; c < 6; ++c)
        uw0[pp * 6 + c] =
            wsrc[(size_t)(g + NG * (6 + pp)) * (DH / 4) + lane16 + 16 * c];
    f32x2 h2[12];
    const float4* h4 = (const float4*)hs;
#pragma unroll
    for (int c = 0; c < 6; ++c) {
      float4 hh = h4[lane16 + 16 * c];   // contiguous 16B/lane: conflict-free
      h2[2 * c]     = f32x2{hh.x, hh.y};
      h2[2 * c + 1] = f32x2{hh.z, hh.w};
    }
    uint2 uw1[12];
#pragma unroll
    for (int pp = 0; pp < 2; ++pp)
#pragma unroll
      for (int c = 0; c < 6; ++c)
        uw1[pp * 6 + c] =
            wsrc[(size_t)(g + NG * (8 + pp)) * (DH / 4) + lane16 + 16 * c];
#pragma unroll
    for (int p = 0; p < 6; ++p) {
      const int r = g + NG * p;
      f32x2 a0 = {0.f, 0.f}, a1 = {0.f, 0.f};
#pragma unroll
      for (int c = 0; c < 6; ++c) {
        uint2 u = lwh[r * LWSTR + lane16 + 16 * c];
        a0 = pkfma(f32x2{blo(u.x), bhi(u.x)}, h2[2 * c], a0);
        a1 = pkfma(f32x2{blo(u.y), bhi(u.y)}, h2[2 * c + 1], a1);
      }
      rs[p] = row16_sum((a0.x + a1.x) + (a0.y + a1.y));
    }
    rs[6] = rowdot(uw0, h2);
    rs[7] = rowdot(uw0 + 6, h2);
    uint2 uw2[12];
#pragma unroll
    for (int pp = 0; pp < 2; ++pp)
#pragma unroll
      for (int c = 0; c < 6; ++c)
        uw2[pp * 6 + c] =
            wsrc[(size_t)(g + NG * (10 + pp)) * (DH / 4) + lane16 + 16 * c];
    rs[8] = rowdot(uw1, h2);
    rs[9] = rowdot(uw1 + 6, h2);
    rs[10] = rowdot(uw2, h2);
    rs[11] = rowdot(uw2 + 6, h2);
  } else {
#pragma unroll
    for (int p = 0; p < RPG; ++p) rs[p] = 0.f;
  }
  if (lane16 == 0) {
#pragma unroll
    for (int p = 0; p < RPG; ++p) {
      const int r = g + NG * p;
      float vv = rs[p] + gzs[r];
      hbs[r] = vv;
      s1 += vv;
      s2 += vv * vv;
    }
  }
}

// Fallback matvec (no workspace): fp32 weights streamed, z from LDS.
__device__ __forceinline__ void matvec_ref(
    const float* __restrict__ Wh_f, const float* __restrict__ Wg_f,
    const float* __restrict__ hs, const float* __restrict__ zsh,
    const float (&bias)[RPG], float* __restrict__ hbs,
    float& s1, float& s2, int g, int lane16, bool with_h)
{
  f32x2 h2[12];
  if (with_h) {
    const float4* h4 = (const float4*)hs;
#pragma unroll
    for (int c = 0; c < 6; ++c) {
      float4 hh = h4[lane16 + 16 * c];
      h2[2 * c]     = f32x2{hh.x, hh.y};
      h2[2 * c + 1] = f32x2{hh.z, hh.w};
    }
  }
  float4 zz[3];
  const float4* z4 = (const float4*)zsh;
#pragma unroll
  for (int c = 0; c < 3; ++c) zz[c] = z4[lane16 + 16 * c];
#pragma unroll 2
  for (int p = 0; p < RPG; ++p) {
    const int r = g + NG * p;
    f32x2 a0 = {0.f, 0.f}, a1 = {0.f, 0.f};
    const float4* wg = (const float4*)Wg_f + (size_t)r * (DG / 4);
#pragma unroll
    for (int c = 0; c < 3; ++c) {
      float4 w = wg[lane16 + 16 * c];
      a0 = pkfma(f32x2{w.x, w.y}, f32x2{zz[c].x, zz[c].y}, a0);
      a1 = pkfma(f32x2{w.z, w.w}, f32x2{zz[c].z, zz[c].w}, a1);
    }
    if (with_h) {
      const float4* wh = (const float4*)Wh_f + (size_t)r * (DH / 4);
#pragma unroll
      for (int c = 0; c < 6; ++c) {
        float4 w = wh[lane16 + 16 * c];
        a0 = pkfma(f32x2{w.x, w.y}, h2[2 * c], a0);
        a1 = pkfma(f32x2{w.z, w.w}, h2[2 * c + 1], a1);
      }
    }
    float acc = row16_sum((a0.x + a1.x) + (a0.y + a1.y));
    if (lane16 == 0) {
      float vv = acc + bias[p];
      hbs[r] = vv;
      s1 += vv;
      s2 += vv * vv;
    }
  }
}

template <bool FULL>
__global__ __launch_bounds__(NT, 2) void fw_rnn_kernel(
    const float* __restrict__ z_seq,    // [T, B, DG]
    const float* __restrict__ Wh_f,     // [DH, DH] fp32
    const float* __restrict__ Wg_f,     // [DH, DG] fp32
    const ushort_t* __restrict__ Wh_b,  // bf16 copy (ws), FULL only
    const float* __restrict__ gz,       // [T, B, DH] Wg.z + b_h, FULL only
    const float* __restrict__ b_h,
    const float* __restrict__ ln_g,
    const float* __restrict__ ln_b,
    const float* __restrict__ alpha_fw,
    float* __restrict__ out)            // [B, DH]
{
  // 96 blocks on 256 CUs -> one block per CU: the full LDS pool is ours.
  __shared__ __align__(16) uint2 lwh[LWROWS * LWSTR];  // 149 KB staged Wh
  __shared__ __align__(16) float hs[DH];
  __shared__ __align__(16) float hbs[DH];
  __shared__ __align__(16) float gzs[DH];           // FULL: Wg.z+b_h for t
  __shared__ __align__(16) float zsh[DG];           // !FULL only
  __shared__ float wlam[NSTEP];
  __shared__ __align__(16) float carr[48];          // entries >= t stay 0
  __shared__ __align__(16) float redA[NWAVE * 2];
  __shared__ __align__(16) float redB[2][32];       // rows padded to 32

  const int tid    = threadIdx.x;
  const int b      = blockIdx.x;
  const int lane   = tid & 63, wv = tid >> 6;
  const int g      = tid >> 4, lane16 = tid & 15;
  const bool owner = (tid < DH);
  const bool zst   = (!FULL) && (tid >= DH) && (tid < DH + DG / 4);

  // stage Wh rows 0..191 into LDS (once)
  if (FULL) {
    const uint2* src = (const uint2*)Wh_b;
    for (int i = tid; i < LWROWS * 96; i += NT) {
      int row = i / 96, col = i - 96 * (i / 96);
      lwh[row * LWSTR + col] = src[(size_t)row * 96 + col];
    }
  }

  float bias[RPG];
#pragma unroll
  for (int p = 0; p < RPG; ++p) bias[p] = 0.f;
  if (!FULL && lane16 == 0) {
#pragma unroll
    for (int p = 0; p < RPG; ++p) bias[p] = b_h[g + NG * p];
  }
  float g_i = 0.f, be_i = 0.f;
  if (owner) { g_i = ln_g[tid]; be_i = ln_b[tid]; }

  const float af   = alpha_fw[0];
  const float kcur = (af >= 0.f) ? (1.f + log1pf(expf(af)))
                                 : (1.f / (1.f + log1pf(expf(-af))));
  const float invD = 1.0f / (float)DH;

  // Register-resident history column: hcol[tau] == h_committed[tau][tid] (owners).
  float hcol[48];
#pragma unroll
  for (int q = 0; q < 48; ++q) hcol[q] = 0.f;
  // phase-A register rows: group g serves tau=g (hregA) and tau=g+32 (hregB)
  float4 hregA[6], hregB[6];
#pragma unroll
  for (int c = 0; c < 6; ++c) {
    hregA[c] = float4{0.f, 0.f, 0.f, 0.f};
    hregB[c] = float4{0.f, 0.f, 0.f, 0.f};
  }

  if (FULL && tid < DH / 4)
    ((float4*)gzs)[tid] = ((const float4*)(gz + (size_t)b * DH))[tid];
  if (!FULL && tid < DG / 4)
    ((float4*)zsh)[tid] = ((const float4*)(z_seq + (size_t)b * DG))[tid];
  if (tid < 48) carr[tid] = 0.f;
  if (tid < 2) { redB[tid][30] = 0.f; redB[tid][31] = 0.f; }
  __syncthreads();

  float Shb = 0.f, Shb2 = 0.f;

  for (int t = 0; t < NSTEP; ++t) {
    // prefetch next step's gz into regs; written to gzs at commit
    float4 gzn = {0.f, 0.f, 0.f, 0.f};
    if (FULL && tid < DH / 4)
      gzn = ((const float4*)(gz + ((size_t)(t + 1) * BB + b) * DH))[tid];

    // ---------- base phase: h_base + fused LN stats ----------
    float s1 = 0.f, s2 = 0.f;
    if (FULL)
      matvec_full(lwh, Wh_b, hs, gzs, hbs, s1, s2, g, lane16, t > 0);
    else
      matvec_ref(Wh_f, Wg_f, hs, zsh, bias, hbs, s1, s2, g, lane16, t > 0);

    // snapshot committed row(s) (hs == h_{t-1} until after barrier (a))
    if (t > 0) {
      if (g == t - 1) {
#pragma unroll
        for (int c = 0; c < 6; ++c) hregA[c] = ((const float4*)hs)[lane16 + 16 * c];
      }
      if (g + NG == t - 1) {
#pragma unroll
        for (int c = 0; c < 6; ++c) hregB[c] = ((const float4*)hs)[lane16 + 16 * c];
      }
    }
    {
      float v0 = wave_sum63(s1);
      float v1 = wave_sum63(s2);
      if (lane == 63) { redA[wv * 2] = v0; redA[wv * 2 + 1] = v1; }
    }
    __syncthreads();  // (a): hbs + redA visible

    float hb = 0.f, hsv = 0.f;
    if (owner) {
      float S1 = 0.f, S2 = 0.f;
      const float4* ra4 = (const float4*)redA;
#pragma unroll
      for (int q = 0; q < 4; ++q) {
        float4 ch = ra4[q];
        S1 += ch.x + ch.z;
        S2 += ch.y + ch.w;
      }
      Shb = S1; Shb2 = S2;
      hb = hbs[tid];
      float m   = S1 * invD;
      float var = S2 * invD - m * m;
      hsv = fmaxf((hb - m) * rsqrtf(var + 1e-5f) * g_i + be_i, 0.f);
      hs[tid] = hsv;
    }
    if (t == 0) {
      // A == 0: settling is identity. Commit, init wlam, stage next inputs.
      if (owner) hcol[0] = hsv;
      if (tid == 0) wlam[0] = 0.5f;
      if (FULL && tid < DH / 4) ((float4*)gzs)[tid] = gzn;
      if (zst)
        ((float4*)zsh)[tid - DH] =
            ((const float4*)(z_seq + ((size_t)1 * BB + b) * DG))[tid - DH];
      __syncthreads();  // (b)
      continue;
    }
    __syncthreads();  // (b): hs visible

    float4 znext;
    if (zst)
      znext = ((const float4*)(z_seq + ((size_t)(t + 1) * BB + b) * DG))[tid - DH];

    // ---------- settling iterations ----------
    for (int s = 0; s < SETI; ++s) {
      // hoisted: v1 = sum(hsv^2) depends only on hsv (final before phase A) --
      // moves a 6-DPP chain off phase B's critical path.
      float v1pre = 0.f;
      if (owner) v1pre = wave_sum63(hsv * hsv);

      // phase A: carr[tau] = wlam_tau * (h_tau . h_s); group g serves tau=g, g+32
      if (g < t) {
        float4 ss[6];
        const float4* s4 = (const float4*)hs;
#pragma unroll
        for (int c = 0; c < 6; ++c) ss[c] = s4[lane16 + 16 * c];
        {
          f32x2 p0 = {0.f, 0.f}, p1 = {0.f, 0.f};
#pragma unroll
          for (int c = 0; c < 6; ++c) {
            p0 = pkfma(f32x2{hregA[c].x, hregA[c].y}, f32x2{ss[c].x, ss[c].y}, p0);
            p1 = pkfma(f32x2{hregA[c].z, hregA[c].w}, f32x2{ss[c].z, ss[c].w}, p1);
          }
          float p = row16_sum((p0.x + p1.x) + (p0.y + p1.y));
          if (lane16 == 0) carr[g] = p * wlam[g];
        }
        if (g + NG < t) {
          f32x2 p0 = {0.f, 0.f}, p1 = {0.f, 0.f};
#pragma unroll
          for (int c = 0; c < 6; ++c) {
            p0 = pkfma(f32x2{hregB[c].x, hregB[c].y}, f32x2{ss[c].x, ss[c].y}, p0);
            p1 = pkfma(f32x2{hregB[c].z, hregB[c].w}, f32x2{ss[c].z, ss[c].w}, p1);
          }
          float p = row16_sum((p0.x + p1.x) + (p0.y + p1.y));
          if (lane16 == 0) carr[g + NG] = p * wlam[g + NG];
        }
      }
      __syncthreads();  // (i): carr visible

      // phase B: owners compute Ah from registers + 4 remaining DPP sums
      float ah = 0.f;
      if (owner) {
        const float4* c4 = (const float4*)carr;
        float a0 = 0.f, a1 = 0.f, a2 = 0.f, a3 = 0.f;
#pragma unroll
        for (int q = 0; q < 12; ++q) {
          float4 cc = c4[q];
          a0 = fmaf(cc.x, hcol[4 * q + 0], a0);
          a1 = fmaf(cc.y, hcol[4 * q + 1], a1);
          a2 = fmaf(cc.z, hcol[4 * q + 2], a2);
          a3 = fmaf(cc.w, hcol[4 * q + 3], a3);
        }
        ah = (a0 + a2) + (a1 + a3);
        float v0 = wave_sum63(hsv * ah);
        float v2 = wave_sum63(ah * ah);
        float v3 = wave_sum63(hb * ah);
        float v4 = wave_sum63(ah);
        if (lane == 63) {
          float* rb = redB[s & 1];
          rb[wv * 5 + 0] = v0; rb[wv * 5 + 1] = v1pre; rb[wv * 5 + 2] = v2;
          rb[wv * 5 + 3] = v3; rb[wv * 5 + 4] = v4;
        }
      }
      __syncthreads();  // (ii): redB visible

      // phase C: gate + analytic LN + commit
      if (owner) {
        const float4* rb4 = (const float4*)redB[s & 1];
        float S[5] = {0.f, 0.f, 0.f, 0.f, 0.f};
#pragma unroll
        for (int q = 0; q < 8; ++q) {
          float4 ch = rb4[q];
          S[(4 * q + 0) % 5] += ch.x;
          S[(4 * q + 1) % 5] += ch.y;
          S[(4 * q + 2) % 5] += ch.z;
          S[(4 * q + 3) % 5] += ch.w;
        }
        float n1 = fmaxf(sqrtf(S[1]), 1e-6f);
        float n2 = fmaxf(sqrtf(S[2]), 1e-6f);
        float R  = fminf(fmaxf(__fdividef(S[0], n1 * n2), 0.f), 1.f);
        float a  = 1.f - __expf(kcur * __logf(1.f - R));
        float beta = 1.f - a * a;
        float mu  = (beta * Shb + a * S[4]) * invD;
        float Exx = (beta * beta * Shb2 + 2.f * beta * a * S[3] + a * a * S[2]) * invD;
        float var = Exx - mu * mu;
        float xv  = beta * hb + a * ah;
        hsv = fmaxf((xv - mu) * rsqrtf(var + 1e-5f) * g_i + be_i, 0.f);
        hs[tid] = hsv;
        if (s == SETI - 1) {
#pragma unroll
          for (int q = 0; q < 48; ++q)
            if (q == t) hcol[q] = hsv;
        }
      }
      if (s == SETI - 1) {
        if (tid < t) wlam[tid] *= 0.9f;
        else if (tid == t) wlam[tid] = 0.5f;
        if (FULL && tid < DH / 4) ((float4*)gzs)[tid] = gzn;
        if (zst) ((float4*)zsh)[tid - DH] = znext;
      }
      __syncthreads();  // (iii)
    }
  }

  // ================= final (query) step (gzs holds gz[NSTEP]) =================
  {
    float s1 = 0.f, s2 = 0.f;
    if (FULL)
      matvec_full(lwh, Wh_b, hs, gzs, hbs, s1, s2, g, lane16, true);
    else
      matvec_ref(Wh_f, Wg_f, hs, zsh, bias, hbs, s1, s2, g, lane16, true);
    if (g + NG == NSTEP - 1) {  // last committed row -> hregB (g = 14)
#pragma unroll
      for (int c = 0; c < 6; ++c) hregB[c] = ((const float4*)hs)[lane16 + 16 * c];
    }
    {
      float v0 = wave_sum63(s1);
      float v1 = wave_sum63(s2);
      if (lane == 63) { redA[wv * 2] = v0; redA[wv * 2 + 1] = v1; }
    }
    __syncthreads();

    float hb = 0.f, hv = 0.f;
    if (owner) {
      float S1 = 0.f, S2 = 0.f;
      const float4* ra4 = (const float4*)redA;
#pragma unroll
      for (int q = 0; q < 4; ++q) {
        float4 ch = ra4[q];
        S1 += ch.x + ch.z;
        S2 += ch.y + ch.w;
      }
      Shb = S1; Shb2 = S2;
      hb = hbs[tid];
      float m   = S1 * invD;
      float var = S2 * invD - m * m;
      hv = fmaxf((hb - m) * rsqrtf(var + 1e-5f) * g_i + be_i, 0.f);
      hs[tid] = hv;
    }
    __syncthreads();

    for (int s = 0; s < SETI; ++s) {
      {
        float4 ss[6];
        const float4* s4 = (const float4*)hs;
#pragma unroll
        for (int c = 0; c < 6; ++c) ss[c] = s4[lane16 + 16 * c];
        {
          f32x2 p0 = {0.f, 0.f}, p1 = {0.f, 0.f};
#pragma unroll
          for (int c = 0; c < 6; ++c) {
            p0 = pkfma(f32x2{hregA[c].x, hregA[c].y}, f32x2{ss[c].x, ss[c].y}, p0);
            p1 = pkfma(f32x2{hregA[c].z, hregA[c].w}, f32x2{ss[c].z, ss[c].w}, p1);
          }
          float p = row16_sum((p0.x + p1.x) + (p0.y + p1.y));
          if (lane16 == 0) carr[g] = p * wlam[g];
        }
        if (g + NG < NSTEP) {
          f32x2 p0 = {0.f, 0.f}, p1 = {0.f, 0.f};
#pragma unroll
          for (int c = 0; c < 6; ++c) {
            p0 = pkfma(f32x2{hregB[c].x, hregB[c].y}, f32x2{ss[c].x, ss[c].y}, p0);
            p1 = pkfma(f32x2{hregB[c].z, hregB[c].w}, f32x2{ss[c].z, ss[c].w}, p1);
          }
          float p = row16_sum((p0.x + p1.x) + (p0.y + p1.y));
          if (lane16 == 0) carr[g + NG] = p * wlam[g + NG];
        }
      }
      __syncthreads();

      float ah = 0.f;
      if (owner) {
        const float4* c4 = (const float4*)carr;
        float a0 = 0.f, a1 = 0.f, a2 = 0.f, a3 = 0.f;
#pragma unroll
        for (int q = 0; q < 12; ++q) {
          float4 cc = c4[q];
          a0 = fmaf(cc.x, hcol[4 * q + 0], a0);
          a1 = fmaf(cc.y, hcol[4 * q + 1], a1);
          a2 = fmaf(cc.z, hcol[4 * q + 2], a2);
          a3 = fmaf(cc.w, hcol[4 * q + 3], a3);
        }
        ah = (a0 + a2) + (a1 + a3);
        float v0 = wave_sum63(ah);
        float v1 = wave_sum63(ah * ah);
        float v2 = wave_sum63(hb * ah);
        if (lane == 63) {
          float* rb = redB[s & 1];
          rb[wv * 5 + 0] = v0; rb[wv * 5 + 1] = v1; rb[wv * 5 + 2] = v2;
        }
      }
      __syncthreads();

      if (owner) {
        const float4* rb4 = (const float4*)redB[s & 1];
        float S[5] = {0.f, 0.f, 0.f, 0.f, 0.f};
#pragma unroll
        for (int q = 0; q < 8; ++q) {
          float4 ch = rb4[q];
          S[(4 * q + 0) % 5] += ch.x;
          S[(4 * q + 1) % 5] += ch.y;
          S[(4 * q + 2) % 5] += ch.z;
          S[(4 * q + 3) % 5] += ch.w;
        }
        // xv = hb + ah : analytic stats (S[0]=sum ah, S[1]=sum ah^2, S[2]=sum hb*ah)
        float Sx  = Shb + S[0];
        float Sxx = Shb2 + 2.f * S[2] + S[1];
        float mu  = Sx * invD;
        float var = Sxx * invD - mu * mu;
        float xv  = hb + ah;
        hv = fmaxf((xv - mu) * rsqrtf(var + 1e-5f) * g_i + be_i, 0.f);
        if (s < SETI - 1) hs[tid] = hv;
      }
      if (s < SETI - 1) __syncthreads();
    }

    if (owner) out[(size_t)b * DH + tid] = hv;
  }
}

// Prologue (one launch): bf16-convert W_h AND compute
// gz[t][b][r] = fp32 W_g[r,:] . z[t][b] + b_h[r].
// grid (BB, 2) x 256 threads: block (b,y) handles 24 t's, z staged in LDS,
// Wg read once per block and register-cached in 3 passes of 8 rows.
__global__ __launch_bounds__(PNT) void prep_kernel(
    const float* __restrict__ z_seq, const float* __restrict__ Wg,
    const float* __restrict__ W_h, const float* __restrict__ b_h,
    ushort_t* __restrict__ Whb, float* __restrict__ gz)
{
  __shared__ __align__(16) float zsh[PTT * DG];
  const int tid = threadIdx.x, b = blockIdx.x;
  const int t0 = blockIdx.y * PTT;
  const int g = tid >> 4, lane16 = tid & 15;

  {
    int lid = ((blockIdx.y * BB + blockIdx.x) * PNT + tid) * 3;
#pragma unroll
    for (int k = 0; k < 3; ++k) {
      int idx = lid + k;
      if (idx < DH * DH) {
        unsigned u = __float_as_uint(W_h[idx]);
        unsigned r = (u + 0x7FFFu + ((u >> 16) & 1u)) >> 16;
        Whb[idx] = (ushort_t)r;
      }
    }
  }

  for (int i = tid; i < PTT * DG / 4; i += PNT) {
    int tt = i / (DG / 4), c = i - tt * (DG / 4);
    ((float4*)zsh)[i] =
        ((const float4*)(z_seq + ((size_t)(t0 + tt) * BB + b) * DG))[c];
  }
  __syncthreads();

  for (int pp = 0; pp < 3; ++pp) {
    const int rbase = 24 * g + 8 * pp;
    float4 w[24];
#pragma unroll
    for (int j = 0; j < 8; ++j)
#pragma unroll
      for (int c = 0; c < 3; ++c)
        w[j * 3 + c] =
            ((const float4*)Wg)[(size_t)(rbase + j) * (DG / 4) + lane16 + 16 * c];
    float4 bh0 = {0.f, 0.f, 0.f, 0.f}, bh1 = {0.f, 0.f, 0.f, 0.f};
    if (lane16 == 0) {
      bh0 = ((const float4*)b_h)[rbase / 4];
      bh1 = ((const float4*)b_h)[rbase / 4 + 1];
    }
    for (int tt = 0; tt < PTT; ++tt) {
      float4 zz[3];
#pragma unroll
      for (int c = 0; c < 3; ++c)
        zz[c] = ((const float4*)zsh)[tt * (DG / 4) + lane16 + 16 * c];
      float rs[8];
#pragma unroll
      for (int j = 0; j < 8; ++j) {
        f32x2 a0 = {0.f, 0.f}, a1 = {0.f, 0.f};
#pragma unroll
        for (int c = 0; c < 3; ++c) {
          a0 = pkfma(f32x2{w[j * 3 + c].x, w[j * 3 + c].y},
                     f32x2{zz[c].x, zz[c].y}, a0);
          a1 = pkfma(f32x2{w[j * 3 + c].z, w[j * 3 + c].w},
                     f32x2{zz[c].z, zz[c].w}, a1);
        }
        rs[j] = row16_sum((a0.x + a1.x) + (a0.y + a1.y));
      }
      if (lane16 == 0) {
        float* grow = gz + ((size_t)(t0 + tt) * BB + b) * DH + rbase;
        ((float4*)grow)[0] =
            float4{rs[0] + bh0.x, rs[1] + bh0.y, rs[2] + bh0.z, rs[3] + bh0.w};
        ((float4*)grow)[1] =
            float4{rs[4] + bh1.x, rs[5] + bh1.y, rs[6] + bh1.z, rs[7] + bh1.w};
      }
    }
  }
}

extern "C" void kernel_launch(void* const* d_in, const int* in_sizes, int n_in,
                              void* d_out, int out_size, void* d_ws, size_t ws_size,
                              hipStream_t stream) {
  const float* z_seq    = (const float*)d_in[0];
  const float* W_h      = (const float*)d_in[1];
  const float* W_g      = (const float*)d_in[2];
  const float* b_h      = (const float*)d_in[3];
  const float* ln_g     = (const float*)d_in[4];
  const float* ln_b     = (const float*)d_in[5];
  const float* alpha_fw = (const float*)d_in[6];
  float* out = (float*)d_out;

  const size_t nWh = (size_t)DH * DH;                              // 147456
  const size_t bf16Bytes = nWh * sizeof(ushort_t);                 // 294912
  const size_t gzBytes   = (size_t)TT * BB * DH * sizeof(float);   // 7077888

  if (ws_size >= bf16Bytes + gzBytes) {
    ushort_t* Whb = (ushort_t*)d_ws;
    float* gz = (float*)((char*)d_ws + bf16Bytes);
    prep_kernel<<<dim3(BB, 2), dim3(PNT), 0, stream>>>(
        z_seq, W_g, W_h, b_h, Whb, gz);
    fw_rnn_kernel<true><<<dim3(BB), dim3(NT), 0, stream>>>(
        z_seq, W_h, W_g, Whb, gz, b_h, ln_g, ln_b, alpha_fw, out);
  } else {
    fw_rnn_kernel<false><<<dim3(BB), dim3(NT), 0, stream>>>(
        z_seq, W_h, W_g, nullptr, nullptr, b_h, ln_g, ln_b, alpha_fw, out);
  }
}